// Round 14
// baseline (518.492 us; speedup 1.0000x reference)
//
#include <hip/hip_runtime.h>

// ---- problem constants --------------------------------------------------
static constexpr int OMODE = 2, PMODE = 4, NZ = 8;
static constexpr int NYX = 512;   // object plane 512x512
static constexpr int NP  = 128;   // probe / tile 128x128
static constexpr int BATCH = 64;
static constexpr int LSTR = 129;  // padded LDS line stride (float2 units)
static constexpr float INV_N2 = 1.0f / 16384.0f;   // 1/(128*128) ifft2 norm

typedef float v2f __attribute__((ext_vector_type(2)));

__device__ __forceinline__ int br7(int x) { return (int)(__brev((unsigned)x) >> 25); }

__device__ __forceinline__ v2f splat2(float s) { return (v2f){s, s}; }
__device__ __forceinline__ v2f swapv(v2f v) { return __builtin_shufflevector(v, v, 1, 0); }
__device__ __forceinline__ v2f cmulv(v2f a, float br_, float bi_) {
  return a * splat2(br_) + swapv(a) * (v2f){-bi_, bi_};
}
__device__ __forceinline__ v2f cmulvv(v2f a, v2f b) {
  return a * splat2(b.x) + swapv(a) * (v2f){-b.y, b.y};
}
// acc += (cx + i*cy) * v
__device__ __forceinline__ v2f cpk(float cx, float cy, v2f v, v2f acc) {
  return acc + splat2(cx) * v + (v2f){-cy, cy} * swapv(v);
}

// ---- cross-lane primitives (validated R4-R13) ---------------------------
template<int CTRL>
__device__ __forceinline__ float dppf(float x) {
  int i = __float_as_int(x);
  int r = __builtin_amdgcn_update_dpp(i, i, CTRL, 0xF, 0xF, false);
  return __int_as_float(r);
}
template<int CTRL>
__device__ __forceinline__ v2f dpp2(v2f v) {
  return (v2f){dppf<CTRL>(v.x), dppf<CTRL>(v.y)};
}
template<int OFS>
__device__ __forceinline__ v2f swz2(v2f v) {
  v2f t;
  t.x = __int_as_float(__builtin_amdgcn_ds_swizzle(__float_as_int(v.x), OFS));
  t.y = __int_as_float(__builtin_amdgcn_ds_swizzle(__float_as_int(v.y), OFS));
  return t;
}
__device__ __forceinline__ v2f bp2(v2f v, int idx) {
  v2f t;
  t.x = __int_as_float(__builtin_amdgcn_ds_bpermute(idx, __float_as_int(v.x)));
  t.y = __int_as_float(__builtin_amdgcn_ds_bpermute(idx, __float_as_int(v.y)));
  return t;
}

// Per-thread twiddles/coefficients, scalars only -> VGPRs (~33 floats).
struct Tw {
  float tc6, ts6;                  // register stage h=64
  float g0;                        // stage 0 (DPP, w=1)
  float g1, dw1r, dw1i;            // stage 1 (DPP + twiddle)
  // DIF radix-4 pair (5,4): z = A1*(p2+gA*x) + B1*(p3+gA*p1)
  float gA54, A54x, A54y, B54x, B54y;
  // DIF radix-4 pair (3,2)
  float gA32, A32x, A32y, B32x, B32y;
  // DIT radix-4 pair (2,3): z = ca*x + c1*p1 + c2*p2 + c3*p3
  float ca23x, ca23y, c123x, c123y, c223x, c223y, c323x, c323y;
  // DIT radix-4 pair (4,5)
  float ca45x, ca45y, c145x, c145y, c245x, c245y, c345x, c345y;
};

// DIF pair coefficients: om = e^{-i th}, th = pi*j/(2H)
// q00: A=1,B=1; q01: A=-om^2,B=om^2; q10: A=om,B=-i*om; q11: A=i*om^3,B=om^3
__device__ __forceinline__ void dif_coef(int j, int b0, int b1, float invH2,
    float& gA, float& Ax, float& Ay, float& Bx, float& By) {
  float th = 3.14159265358979f * (float)j * invH2;
  float s1, c1, s2, c2, s3, c3;
  __sincosf(th, &s1, &c1);
  __sincosf(2.f * th, &s2, &c2);
  __sincosf(3.f * th, &s3, &c3);
  gA = b1 ? -1.f : 1.f;
  if (!b1) {
    if (!b0) { Ax = 1.f;  Ay = 0.f;  Bx = 1.f;  By = 0.f; }
    else     { Ax = -c2;  Ay = s2;   Bx = c2;   By = -s2; }
  } else {
    if (!b0) { Ax = c1;   Ay = -s1;  Bx = -s1;  By = -c1; }
    else     { Ax = s3;   Ay = c3;   Bx = c3;   By = -s3; }
  }
}
// DIT pair coefficients: om = e^{+i th}
// q00: (1, om^2, om, om^3); q01: (-om^2, 1, -i*om^3, i*om)
// q10: (-om, -om^3, 1, om^2); q11: (i*om^3, -i*om, -om^2, 1)
__device__ __forceinline__ void dit_coef(int j, int b0, int b1, float invH2,
    float& cax, float& cay, float& c1x, float& c1y,
    float& c2x, float& c2y, float& c3x, float& c3y) {
  float th = 3.14159265358979f * (float)j * invH2;
  float s1, c1, s2, c2, s3, c3;
  __sincosf(th, &s1, &c1);
  __sincosf(2.f * th, &s2, &c2);
  __sincosf(3.f * th, &s3, &c3);
  if (!b1) {
    if (!b0) { cax=1.f;  cay=0.f;  c1x=c2;  c1y=s2;  c2x=c1;  c2y=s1;  c3x=c3;  c3y=s3; }
    else     { cax=-c2;  cay=-s2;  c1x=1.f; c1y=0.f; c2x=s3;  c2y=-c3; c3x=-s1; c3y=c1; }
  } else {
    if (!b0) { cax=-c1;  cay=-s1;  c1x=-c3; c1y=-s3; c2x=1.f; c2y=0.f; c3x=c2;  c3y=s2; }
    else     { cax=-s3;  cay=c3;   c1x=s1;  c1y=-c1; c2x=-c2; c2y=-s2; c3x=1.f; c3y=0.f; }
  }
}

__device__ __forceinline__ void init_tw(Tw& tw, int lane) {
  tw.g0 = (lane & 1) ? -1.f : 1.f;
  {
    int j = lane & 1; bool up = (lane >> 1) & 1;
    float s, c;
    __sincosf(1.5707963268f * (float)j, &s, &c);
    tw.g1   = up ? -1.f : 1.f;
    tw.dw1r = up ? c : 1.f;
    tw.dw1i = up ? -s : 0.f;
  }
  __sincosf(3.14159265358979f * (float)lane * (1.f / 64.f), &tw.ts6, &tw.tc6);
  dif_coef(lane & 15, (lane >> 4) & 1, (lane >> 5) & 1, 1.f / 32.f,
           tw.gA54, tw.A54x, tw.A54y, tw.B54x, tw.B54y);
  dif_coef(lane & 3, (lane >> 2) & 1, (lane >> 3) & 1, 1.f / 8.f,
           tw.gA32, tw.A32x, tw.A32y, tw.B32x, tw.B32y);
  dit_coef(lane & 3, (lane >> 2) & 1, (lane >> 3) & 1, 1.f / 8.f,
           tw.ca23x, tw.ca23y, tw.c123x, tw.c123y, tw.c223x, tw.c223y, tw.c323x, tw.c323y);
  dit_coef(lane & 15, (lane >> 4) & 1, (lane >> 5) & 1, 1.f / 32.f,
           tw.ca45x, tw.ca45y, tw.c145x, tw.c145y, tw.c245x, tw.c245y, tw.c345x, tw.c345y);
}

// ---- radix-4 merged stage-pairs, grouped over 8 lines -------------------
// DIF: z = A1*(p2 + gA*x) + B1*(p3 + gA*p1)
#define DIF_R4_PAIR(X, EX1, EX2, EX3, GA, AX, AY, BX, BY)                   \
  {                                                                         \
    v2f p1[8], p2[8], p3[8];                                                \
    _Pragma("unroll") for (int k = 0; k < 8; ++k) p1[k] = EX1(X[k]);        \
    _Pragma("unroll") for (int k = 0; k < 8; ++k) p2[k] = EX2(X[k]);        \
    _Pragma("unroll") for (int k = 0; k < 8; ++k) p3[k] = EX3(X[k]);        \
    _Pragma("unroll") for (int k = 0; k < 8; ++k) {                         \
      v2f U = p2[k] + splat2(GA) * X[k];                                    \
      v2f V = p3[k] + splat2(GA) * p1[k];                                   \
      v2f z = splat2(AX) * U + (v2f){-(AY), (AY)} * swapv(U);               \
      X[k] = cpk(BX, BY, V, z);                                             \
    }                                                                       \
  }

// DIT: z = ca*x + c1*p1 + c2*p2 + c3*p3
#define DIT_R4_PAIR(X, EX1, EX2, EX3, CAX, CAY, C1X, C1Y, C2X, C2Y, C3X, C3Y) \
  {                                                                         \
    v2f p1[8], p2[8], p3[8];                                                \
    _Pragma("unroll") for (int k = 0; k < 8; ++k) p1[k] = EX1(X[k]);        \
    _Pragma("unroll") for (int k = 0; k < 8; ++k) p2[k] = EX2(X[k]);        \
    _Pragma("unroll") for (int k = 0; k < 8; ++k) p3[k] = EX3(X[k]);        \
    _Pragma("unroll") for (int k = 0; k < 8; ++k) {                         \
      v2f z = splat2(CAX) * X[k] + (v2f){-(CAY), (CAY)} * swapv(X[k]);      \
      z = cpk(C1X, C1Y, p1[k], z);                                          \
      z = cpk(C2X, C2Y, p2[k], z);                                          \
      X[k] = cpk(C3X, C3Y, p3[k], z);                                       \
    }                                                                       \
  }

#define EX_SWZ4(v)  swz2<0x101F>(v)
#define EX_SWZ8(v)  swz2<0x201F>(v)
#define EX_SWZ12(v) swz2<0x301F>(v)
#define EX_SWZ16(v) swz2<0x401F>(v)
#define EX_BP32(v)  bp2(v, bp32)
#define EX_BP48(v)  bp2(v, bp48)

// Forward 128-pt DIF x8: natural-order input -> bit-reversed-order slots.
__device__ __forceinline__ void dif128_x8(v2f A[8], v2f B[8], const Tw& tw,
                                          int bp32, int bp48) {
#pragma unroll
  for (int k = 0; k < 8; ++k) {  // register stage h=64
    v2f d = A[k] - B[k];
    A[k] = A[k] + B[k];
    B[k] = d * splat2(tw.tc6) + swapv(d) * (v2f){tw.ts6, -tw.ts6};
  }
  DIF_R4_PAIR(A, EX_SWZ16, EX_BP32, EX_BP48, tw.gA54, tw.A54x, tw.A54y, tw.B54x, tw.B54y)
  DIF_R4_PAIR(B, EX_SWZ16, EX_BP32, EX_BP48, tw.gA54, tw.A54x, tw.A54y, tw.B54x, tw.B54y)
  DIF_R4_PAIR(A, EX_SWZ4, EX_SWZ8, EX_SWZ12, tw.gA32, tw.A32x, tw.A32y, tw.B32x, tw.B32y)
  DIF_R4_PAIR(B, EX_SWZ4, EX_SWZ8, EX_SWZ12, tw.gA32, tw.A32x, tw.A32y, tw.B32x, tw.B32y)
#pragma unroll
  for (int k = 0; k < 8; ++k) {  // stage 1 (DPP + twiddle) + stage 0 (DPP, w=1)
    v2f d;
    d = dpp2<0x4E>(A[k]) + splat2(tw.g1) * A[k];
    A[k] = d * splat2(tw.dw1r) + swapv(d) * (v2f){-tw.dw1i, tw.dw1i};
    d = dpp2<0x4E>(B[k]) + splat2(tw.g1) * B[k];
    B[k] = d * splat2(tw.dw1r) + swapv(d) * (v2f){-tw.dw1i, tw.dw1i};
    A[k] = dpp2<0xB1>(A[k]) + splat2(tw.g0) * A[k];
    B[k] = dpp2<0xB1>(B[k]) + splat2(tw.g0) * B[k];
  }
}

// Inverse (unnormalized) 128-pt DIT x8: bit-reversed slots -> natural order.
__device__ __forceinline__ void dit128_x8(v2f A[8], v2f B[8], const Tw& tw,
                                          int bp32, int bp48) {
#pragma unroll
  for (int k = 0; k < 8; ++k) {  // stage 0 (DPP, w=1) + stage 1 (twiddle + DPP)
    A[k] = dpp2<0xB1>(A[k]) + splat2(tw.g0) * A[k];
    B[k] = dpp2<0xB1>(B[k]) + splat2(tw.g0) * B[k];
    v2f m;
    m = A[k] * splat2(tw.dw1r) + swapv(A[k]) * (v2f){tw.dw1i, -tw.dw1i};
    A[k] = dpp2<0x4E>(m) + splat2(tw.g1) * m;
    m = B[k] * splat2(tw.dw1r) + swapv(B[k]) * (v2f){tw.dw1i, -tw.dw1i};
    B[k] = dpp2<0x4E>(m) + splat2(tw.g1) * m;
  }
  DIT_R4_PAIR(A, EX_SWZ4, EX_SWZ8, EX_SWZ12, tw.ca23x, tw.ca23y, tw.c123x, tw.c123y,
              tw.c223x, tw.c223y, tw.c323x, tw.c323y)
  DIT_R4_PAIR(B, EX_SWZ4, EX_SWZ8, EX_SWZ12, tw.ca23x, tw.ca23y, tw.c123x, tw.c123y,
              tw.c223x, tw.c223y, tw.c323x, tw.c323y)
  DIT_R4_PAIR(A, EX_SWZ16, EX_BP32, EX_BP48, tw.ca45x, tw.ca45y, tw.c145x, tw.c145y,
              tw.c245x, tw.c245y, tw.c345x, tw.c345y)
  DIT_R4_PAIR(B, EX_SWZ16, EX_BP32, EX_BP48, tw.ca45x, tw.ca45y, tw.c145x, tw.c145y,
              tw.c245x, tw.c245y, tw.c345x, tw.c345y)
#pragma unroll
  for (int k = 0; k < 8; ++k) {  // register stage h=64
    v2f m = B[k] * splat2(tw.tc6) + swapv(B[k]) * (v2f){-tw.ts6, tw.ts6};
    B[k] = A[k] - m;
    A[k] = A[k] + m;
  }
}

// Pre-scramble H into workspace: hp[px][py] = H[br(py)][br(px)] * (1/N^2).
__global__ void __launch_bounds__(256) init_hpre(const float* __restrict__ H,
                                                 float2* __restrict__ hp) {
  int i = blockIdx.x * blockDim.x + threadIdx.x;
  if (i >= NP * NP) return;
  int px = i >> 7, py = i & (NP - 1);
  int ky = br7(py), kx = br7(px);
  hp[px * NP + py] = make_float2(H[(ky * NP + kx) * 2 + 0] * INV_N2,
                                 H[(ky * NP + kx) * 2 + 1] * INV_N2);
}

// Per-n shift ramps at bit-reversed slot positions.
__global__ void __launch_bounds__(256) init_ramp(const float* __restrict__ shifts,
                                                 const int* __restrict__ indices,
                                                 float2* __restrict__ rampy,
                                                 float2* __restrict__ rampx) {
  int i = blockIdx.x * blockDim.x + threadIdx.x;
  if (i >= 2 * BATCH * NP) return;
  int which = (i >= BATCH * NP) ? 1 : 0;
  int r = i - which * BATCH * NP;
  int n = r >> 7, slot = r & (NP - 1);
  int pos = indices[n];
  float sh = shifts[2 * pos + which];
  int k = br7(slot);
  float f = (float)(k < 64 ? k : k - 128) * (1.f / 128.f);
  float s, c;
  __sincosf(-6.28318530717959f * f * sh, &s, &c);
  if (!which) rampy[n * NP + slot] = make_float2(c * INV_N2, s * INV_N2);
  else        rampx[n * NP + slot] = make_float2(c, s);
}

// Precompute T = obja * exp(i*objp) over the full object volume.
__global__ void __launch_bounds__(256) init_T(const float* __restrict__ obja,
                                              const float* __restrict__ objp,
                                              float2* __restrict__ T) {
  int i = blockIdx.x * 256 + threadIdx.x;
  if (i >= OMODE * NZ * NYX * NYX) return;
  float a = obja[i], ph = objp[i];
  float s, c;
  __sincosf(ph, &s, &c);
  T[i] = make_float2(a * c, a * s);
}

// Sum the 8 (o,p) partials per batch element, applying omode occupancy here.
// part tile is TRANSPOSED: [blk][kx][ky].
__global__ void __launch_bounds__(256) reduce_dp(const float* __restrict__ part,
                                                 const float* __restrict__ occu,
                                                 float* __restrict__ dp) {
  int i = blockIdx.x * 256 + threadIdx.x;
  if (i >= BATCH * NP * NP) return;
  int n = i >> 14;
  int r = i & (NP * NP - 1);
  int ky = r >> 7, kx = r & (NP - 1);
  const float* b = part + ((size_t)n * 8 << 14) + (kx << 7) + ky;
  float w0 = occu[0], w1 = occu[1];
  float s = 0.f;
#pragma unroll
  for (int j = 0; j < 8; ++j) s = fmaf(b[(size_t)j << 14], (j < 4 ? w0 : w1), s);
  dp[i] = s;
}

// Prep: compute real-space sub-pixel-shifted probe per (n,p) -> ws.
__global__ void
__attribute__((amdgpu_flat_work_group_size(512, 512), amdgpu_waves_per_eu(2, 2)))
shift_probe(const float* __restrict__ probe,
            const float2* __restrict__ rampy, const float2* __restrict__ rampx,
            float2* __restrict__ ps)
{
  extern __shared__ v2f fld[];
  const int blk  = blockIdx.x;             // n*4 + p
  const int n    = blk >> 2;
  const int p    = blk & 3;
  const int tid  = threadIdx.x;
  const int wid  = tid >> 6;               // 8 waves
  const int lane = tid & 63;
  const int bp32 = (lane ^ 32) << 2;
  const int bp48 = (lane ^ 48) << 2;

  Tw tw;
  init_tw(tw, lane);

  const v2f* probe2 = (const v2f*)probe;
#pragma unroll 1
  for (int k0 = 0; k0 < 16; k0 += 8) {
    int r0 = wid * 16 + k0;
    v2f A[8], B[8];
#pragma unroll
    for (int kk = 0; kk < 8; ++kk) {
      A[kk] = probe2[(p * NP + r0 + kk) * NP + lane];
      B[kk] = probe2[(p * NP + r0 + kk) * NP + lane + 64];
    }
    dif128_x8(A, B, tw, bp32, bp48);
#pragma unroll
    for (int kk = 0; kk < 8; ++kk) {
      fld[(r0 + kk) * LSTR + lane]      = A[kk];
      fld[(r0 + kk) * LSTR + lane + 64] = B[kk];
    }
  }
  __syncthreads();

  {
    float2 t0 = rampy[n * NP + lane];
    float2 t1 = rampy[n * NP + lane + 64];
    v2f ry0 = (v2f){t0.x, t0.y}, ry1 = (v2f){t1.x, t1.y};
#pragma unroll 1
    for (int k0 = 0; k0 < 16; k0 += 8) {
      int c0 = wid * 16 + k0;
      float2 rx[8];
#pragma unroll
      for (int kk = 0; kk < 8; ++kk) rx[kk] = rampx[n * NP + c0 + kk];
      v2f A[8], B[8];
#pragma unroll
      for (int kk = 0; kk < 8; ++kk) {
        A[kk] = fld[lane * LSTR + c0 + kk];
        B[kk] = fld[(lane + 64) * LSTR + c0 + kk];
      }
      dif128_x8(A, B, tw, bp32, bp48);
#pragma unroll
      for (int kk = 0; kk < 8; ++kk) {
        v2f m;
        m = cmulv(ry0, rx[kk].x, rx[kk].y); A[kk] = cmulvv(A[kk], m);
        m = cmulv(ry1, rx[kk].x, rx[kk].y); B[kk] = cmulvv(B[kk], m);
      }
      dit128_x8(A, B, tw, bp32, bp48);
#pragma unroll
      for (int kk = 0; kk < 8; ++kk) {
        fld[lane * LSTR + c0 + kk]        = A[kk];
        fld[(lane + 64) * LSTR + c0 + kk] = B[kk];
      }
    }
    __syncthreads();
  }

  float2* out = ps + ((size_t)blk << 14);
#pragma unroll 1
  for (int k0 = 0; k0 < 16; k0 += 8) {
    int r0 = wid * 16 + k0;
    v2f A[8], B[8];
#pragma unroll
    for (int kk = 0; kk < 8; ++kk) {
      A[kk] = fld[(r0 + kk) * LSTR + lane];
      B[kk] = fld[(r0 + kk) * LSTR + lane + 64];
    }
    dit128_x8(A, B, tw, bp32, bp48);
#pragma unroll
    for (int kk = 0; kk < 8; ++kk) {
      out[(r0 + kk) * NP + lane]      = make_float2(A[kk].x, A[kk].y);
      out[(r0 + kk) * NP + lane + 64] = make_float2(B[kk].x, B[kk].y);
    }
  }
}

__global__ void
__attribute__((amdgpu_flat_work_group_size(512, 512), amdgpu_waves_per_eu(2, 2)))
ptycho_chain(
    const float* __restrict__ obja, const float* __restrict__ objp,
    const float* __restrict__ probe, const float* __restrict__ shifts,
    const float* __restrict__ H, const float2* __restrict__ hpre,
    const float2* __restrict__ rampy, const float2* __restrict__ rampx,
    const float2* __restrict__ Tpre, const float2* __restrict__ Ps,
    const float* __restrict__ occu, const int* __restrict__ indices,
    const int* __restrict__ crop, float* __restrict__ dp,
    float* __restrict__ part, int mode_ws, int mode_T, int mode_ps)
{
  extern __shared__ v2f fld[];             // [128][LSTR] interleaved re/im

  const int blk  = blockIdx.x;             // n*8 + o*4 + p
  const int n    = blk >> 3;
  const int o    = (blk >> 2) & 1;
  const int p    = blk & 3;
  const int tid  = threadIdx.x;
  const int wid  = tid >> 6;               // 8 waves
  const int lane = tid & 63;
  const int bp32 = (lane ^ 32) << 2;
  const int bp48 = (lane ^ 48) << 2;

  const int   pos = indices[n];
  const int   cy  = crop[2 * pos + 0];
  const int   cx  = crop[2 * pos + 1];
  const float wocc = occu[o];

  Tw tw;
  init_tw(tw, lane);

  // fallback-only multiplies (no workspace)
  auto ramp_mul_fb = [&](v2f& A, v2f& B, int c) {
    float sh0v = shifts[2 * pos], sh1v = shifts[2 * pos + 1];
    int kxc = br7(c);
    float fx = (float)(kxc < 64 ? kxc : kxc - 128) * (1.f / 128.f);
    int ky0 = br7(lane);
    float fy0 = (float)(ky0 < 64 ? ky0 : ky0 - 128) * (1.f / 128.f);
    int ky1 = ky0 + 1;
    float fy1 = (float)(ky1 < 64 ? ky1 : ky1 - 128) * (1.f / 128.f);
    float com = fx * sh1v;
    float s0, c0_, s1, c1_;
    __sincosf(-6.28318530717959f * (fy0 * sh0v + com), &s0, &c0_);
    __sincosf(-6.28318530717959f * (fy1 * sh0v + com), &s1, &c1_);
    A = cmulv(A, c0_ * INV_N2, s0 * INV_N2);
    B = cmulv(B, c1_ * INV_N2, s1 * INV_N2);
  };
  auto h_mul_fb = [&](v2f& A, v2f& B, int c) {
    int kx = br7(c), ky0 = br7(lane);
    float hr0 = H[(ky0 * NP + kx) * 2], hi0 = H[(ky0 * NP + kx) * 2 + 1];
    float hr1 = H[((ky0 + 1) * NP + kx) * 2], hi1 = H[((ky0 + 1) * NP + kx) * 2 + 1];
    A = cmulv(A, hr0 * INV_N2, hi0 * INV_N2);
    B = cmulv(B, hr1 * INV_N2, hi1 * INV_N2);
  };

  // ---- column phase: Fcol, freq multiply, invCol ------------------------
  auto cphase = [&](int mode) {
    v2f ry0, ry1;
    if (mode == 0 && mode_ws) {
      float2 t0 = rampy[n * NP + lane];
      float2 t1 = rampy[n * NP + lane + 64];
      ry0 = (v2f){t0.x, t0.y}; ry1 = (v2f){t1.x, t1.y};
    }
#pragma unroll 1
    for (int k0 = 0; k0 < 16; k0 += 8) {
      int c0 = wid * 16 + k0;
      float2 h0[8], h1[8], rx[8];
      if (mode == 1 && mode_ws) {
#pragma unroll
        for (int kk = 0; kk < 8; ++kk) {
          h0[kk] = hpre[(c0 + kk) * NP + lane];
          h1[kk] = hpre[(c0 + kk) * NP + lane + 64];
        }
      }
      if (mode == 0 && mode_ws) {
#pragma unroll
        for (int kk = 0; kk < 8; ++kk) rx[kk] = rampx[n * NP + c0 + kk];
      }
      v2f A[8], B[8];
#pragma unroll
      for (int kk = 0; kk < 8; ++kk) {
        A[kk] = fld[lane * LSTR + c0 + kk];
        B[kk] = fld[(lane + 64) * LSTR + c0 + kk];
      }
      dif128_x8(A, B, tw, bp32, bp48);
      if (mode == 0) {
        if (mode_ws) {
#pragma unroll
          for (int kk = 0; kk < 8; ++kk) {
            v2f m;
            m = cmulv(ry0, rx[kk].x, rx[kk].y); A[kk] = cmulvv(A[kk], m);
            m = cmulv(ry1, rx[kk].x, rx[kk].y); B[kk] = cmulvv(B[kk], m);
          }
        } else {
#pragma unroll
          for (int kk = 0; kk < 8; ++kk) ramp_mul_fb(A[kk], B[kk], c0 + kk);
        }
      } else {
        if (mode_ws) {
#pragma unroll
          for (int kk = 0; kk < 8; ++kk) {
            A[kk] = cmulv(A[kk], h0[kk].x, h0[kk].y);
            B[kk] = cmulv(B[kk], h1[kk].x, h1[kk].y);
          }
        } else {
#pragma unroll
          for (int kk = 0; kk < 8; ++kk) h_mul_fb(A[kk], B[kk], c0 + kk);
        }
      }
      dit128_x8(A, B, tw, bp32, bp48);
#pragma unroll
      for (int kk = 0; kk < 8; ++kk) {
        fld[lane * LSTR + c0 + kk]        = A[kk];
        fld[(lane + 64) * LSTR + c0 + kk] = B[kk];
      }
    }
    __syncthreads();
  };

  // ---- row phase: invRow, multiply T(z), Frow ---------------------------
  auto rphase = [&](int z) {
#pragma unroll 1
    for (int k0 = 0; k0 < 16; k0 += 8) {
      int r0 = wid * 16 + k0;
      size_t ob = ((size_t)(o * NZ + z) * NYX + (size_t)(cy + r0)) * NYX + cx;
      v2f A[8], B[8];
#pragma unroll
      for (int kk = 0; kk < 8; ++kk) {
        A[kk] = fld[(r0 + kk) * LSTR + lane];
        B[kk] = fld[(r0 + kk) * LSTR + lane + 64];
      }
      if (mode_T) {
        float2 t0[8], t1[8];
#pragma unroll
        for (int kk = 0; kk < 8; ++kk) {
          t0[kk] = Tpre[ob + (size_t)kk * NYX + lane];
          t1[kk] = Tpre[ob + (size_t)kk * NYX + lane + 64];
        }
        dit128_x8(A, B, tw, bp32, bp48);
#pragma unroll
        for (int kk = 0; kk < 8; ++kk) {
          A[kk] = cmulv(A[kk], t0[kk].x, t0[kk].y);
          B[kk] = cmulv(B[kk], t1[kk].x, t1[kk].y);
        }
      } else {
        float pa0[8], ph0[8], pa1[8], ph1[8];
#pragma unroll
        for (int kk = 0; kk < 8; ++kk) {
          pa0[kk] = obja[ob + (size_t)kk * NYX + lane];
          ph0[kk] = objp[ob + (size_t)kk * NYX + lane];
          pa1[kk] = obja[ob + (size_t)kk * NYX + lane + 64];
          ph1[kk] = objp[ob + (size_t)kk * NYX + lane + 64];
        }
        dit128_x8(A, B, tw, bp32, bp48);
#pragma unroll
        for (int kk = 0; kk < 8; ++kk) {
          float s, c;
          __sincosf(ph0[kk], &s, &c); A[kk] = cmulv(A[kk], pa0[kk] * c, pa0[kk] * s);
          __sincosf(ph1[kk], &s, &c); B[kk] = cmulv(B[kk], pa1[kk] * c, pa1[kk] * s);
        }
      }
      dif128_x8(A, B, tw, bp32, bp48);
#pragma unroll
      for (int kk = 0; kk < 8; ++kk) {
        fld[(r0 + kk) * LSTR + lane]      = A[kk];
        fld[(r0 + kk) * LSTR + lane + 64] = B[kk];
      }
    }
    __syncthreads();
  };

  if (mode_ps) {
    // fused first phase: load shifted probe (real space), x T(z=0), Frow
    const float2* psf = Ps + ((size_t)((n << 2) + p) << 14);
#pragma unroll 1
    for (int k0 = 0; k0 < 16; k0 += 8) {
      int r0 = wid * 16 + k0;
      size_t ob = ((size_t)(o * NZ + 0) * NYX + (size_t)(cy + r0)) * NYX + cx;
      v2f A[8], B[8];
#pragma unroll
      for (int kk = 0; kk < 8; ++kk) {
        float2 p0 = psf[(r0 + kk) * NP + lane];
        float2 p1 = psf[(r0 + kk) * NP + lane + 64];
        float2 t0 = Tpre[ob + (size_t)kk * NYX + lane];
        float2 t1 = Tpre[ob + (size_t)kk * NYX + lane + 64];
        A[kk] = cmulv((v2f){p0.x, p0.y}, t0.x, t0.y);
        B[kk] = cmulv((v2f){p1.x, p1.y}, t1.x, t1.y);
      }
      dif128_x8(A, B, tw, bp32, bp48);
#pragma unroll
      for (int kk = 0; kk < 8; ++kk) {
        fld[(r0 + kk) * LSTR + lane]      = A[kk];
        fld[(r0 + kk) * LSTR + lane + 64] = B[kk];
      }
    }
    __syncthreads();
  } else {
    const v2f* probe2 = (const v2f*)probe;
#pragma unroll 1
    for (int k0 = 0; k0 < 16; k0 += 8) {
      int r0 = wid * 16 + k0;
      v2f A[8], B[8];
#pragma unroll
      for (int kk = 0; kk < 8; ++kk) {
        A[kk] = probe2[(p * NP + r0 + kk) * NP + lane];
        B[kk] = probe2[(p * NP + r0 + kk) * NP + lane + 64];
      }
      dif128_x8(A, B, tw, bp32, bp48);
#pragma unroll
      for (int kk = 0; kk < 8; ++kk) {
        fld[(r0 + kk) * LSTR + lane]      = A[kk];
        fld[(r0 + kk) * LSTR + lane + 64] = B[kk];
      }
    }
    __syncthreads();
    cphase(0);
    rphase(0);
  }

#pragma unroll 1
  for (int z = 1; z < NZ; ++z) {
    cphase(1);      // Fcol + H + invCol     (propagation z-1 -> z)
    rphase(z);      // invRow + Tz + Frow
  }

  // ---- final column FFT -> |.|^2 -> store (transposed part tile) --------
#pragma unroll 1
  for (int k0 = 0; k0 < 16; k0 += 8) {
    int c0 = wid * 16 + k0;
    v2f A[8], B[8];
#pragma unroll
    for (int kk = 0; kk < 8; ++kk) {
      A[kk] = fld[lane * LSTR + c0 + kk];
      B[kk] = fld[(lane + 64) * LSTR + c0 + kk];
    }
    dif128_x8(A, B, tw, bp32, bp48);
    int ky0 = br7(lane);
#pragma unroll
    for (int kk = 0; kk < 8; ++kk) {
      float m0 = fmaf(A[kk].x, A[kk].x, A[kk].y * A[kk].y);
      float m1 = fmaf(B[kk].x, B[kk].x, B[kk].y * B[kk].y);
      if (mode_ws) {
        size_t b0 = ((size_t)blk << 14) + (size_t)br7(c0 + kk) * NP;
        part[b0 + ky0]     = m0;    // occupancy weight applied in reduce_dp
        part[b0 + ky0 + 1] = m1;
      } else {
        size_t base = ((size_t)n << 14);
        atomicAdd(&dp[base + (size_t)ky0 * NP + br7(c0 + kk)],       m0 * wocc);
        atomicAdd(&dp[base + (size_t)(ky0 + 1) * NP + br7(c0 + kk)], m1 * wocc);
      }
    }
  }
}

extern "C" void kernel_launch(void* const* d_in, const int* in_sizes, int n_in,
                              void* d_out, int out_size, void* d_ws, size_t ws_size,
                              hipStream_t stream) {
  const float* obja   = (const float*)d_in[0];
  const float* objp   = (const float*)d_in[1];
  const float* probe  = (const float*)d_in[2];
  const float* shifts = (const float*)d_in[3];
  const float* H      = (const float*)d_in[4];
  const float* occu   = (const float*)d_in[5];
  const int*   indices = (const int*)d_in[6];
  const int*   crop    = (const int*)d_in[7];
  float* dp = (float*)d_out;

  const size_t part_bytes  = (size_t)BATCH * OMODE * PMODE * NP * NP * sizeof(float); // 32 MB
  const size_t hpre_bytes  = (size_t)NP * NP * sizeof(float2);                        // 128 KB
  const size_t ramp_bytes  = (size_t)BATCH * NP * sizeof(float2);                     // 64 KB each
  const size_t T_bytes     = (size_t)OMODE * NZ * NYX * NYX * sizeof(float2);         // 33.5 MB
  const size_t ps_bytes    = (size_t)BATCH * PMODE * NP * NP * sizeof(float2);        // 16.8 MB
  const size_t need_ws = part_bytes + hpre_bytes + 2 * ramp_bytes;
  const size_t need_T  = need_ws + T_bytes;
  const size_t need_ps = need_T + ps_bytes;

  int mode_ws = (ws_size >= need_ws) ? 1 : 0;
  int mode_T  = (ws_size >= need_T) ? 1 : 0;
  int mode_ps = (ws_size >= need_ps) ? 1 : 0;
  float*  part  = (float*)d_ws;
  float2* hpre  = (float2*)((char*)d_ws + part_bytes);
  float2* rampy = (float2*)((char*)d_ws + part_bytes + hpre_bytes);
  float2* rampx = (float2*)((char*)d_ws + part_bytes + hpre_bytes + ramp_bytes);
  float2* Tpre  = (float2*)((char*)d_ws + need_ws);
  float2* Ps    = (float2*)((char*)d_ws + need_T);

  if (mode_ws) {
    hipLaunchKernelGGL(init_hpre, dim3((NP * NP + 255) / 256), dim3(256), 0,
                       stream, H, hpre);
    hipLaunchKernelGGL(init_ramp, dim3((2 * BATCH * NP + 255) / 256), dim3(256), 0,
                       stream, shifts, indices, rampy, rampx);
  } else {
    hipMemsetAsync(d_out, 0, (size_t)out_size * sizeof(float), stream);
  }
  if (mode_T) {
    hipLaunchKernelGGL(init_T, dim3((OMODE * NZ * NYX * NYX + 255) / 256), dim3(256),
                       0, stream, obja, objp, Tpre);
  }

  const int lds_bytes = NP * LSTR * (int)sizeof(float2);  // 132096
  if (mode_ps) {
    hipFuncSetAttribute((const void*)shift_probe,
                        hipFuncAttributeMaxDynamicSharedMemorySize, lds_bytes);
    hipLaunchKernelGGL(shift_probe, dim3(BATCH * PMODE), dim3(512),
                       lds_bytes, stream, probe, rampy, rampx, Ps);
  }

  hipFuncSetAttribute((const void*)ptycho_chain,
                      hipFuncAttributeMaxDynamicSharedMemorySize, lds_bytes);
  hipLaunchKernelGGL(ptycho_chain, dim3(BATCH * OMODE * PMODE), dim3(512),
                     lds_bytes, stream,
                     obja, objp, probe, shifts, H, hpre, rampy, rampx, Tpre, Ps,
                     occu, indices, crop, dp, part, mode_ws, mode_T, mode_ps);
  if (mode_ws) {
    hipLaunchKernelGGL(reduce_dp, dim3((BATCH * NP * NP + 255) / 256), dim3(256),
                       0, stream, part, occu, dp);
  }
}

// Round 15
// 377.087 us; speedup vs baseline: 1.3750x; 1.3750x over previous
//
#include <hip/hip_runtime.h>

// ---- problem constants --------------------------------------------------
static constexpr int OMODE = 2, PMODE = 4, NZ = 8;
static constexpr int NYX = 512;   // object plane 512x512
static constexpr int NP  = 128;   // probe / tile 128x128
static constexpr int BATCH = 64;
static constexpr int LSTR = 129;  // padded LDS line stride (float2 units)
static constexpr float INV_N2 = 1.0f / 16384.0f;   // 1/(128*128) ifft2 norm

typedef float v2f __attribute__((ext_vector_type(2)));

__device__ __forceinline__ int br7(int x) { return (int)(__brev((unsigned)x) >> 25); }

__device__ __forceinline__ v2f splat2(float s) { return (v2f){s, s}; }
__device__ __forceinline__ v2f swapv(v2f v) { return __builtin_shufflevector(v, v, 1, 0); }
__device__ __forceinline__ v2f cmulv(v2f a, float br_, float bi_) {
  return a * splat2(br_) + swapv(a) * (v2f){-bi_, bi_};
}
__device__ __forceinline__ v2f cmulvv(v2f a, v2f b) {
  return a * splat2(b.x) + swapv(a) * (v2f){-b.y, b.y};
}

// ---- cross-lane exchange ------------------------------------------------
template<int CTRL>
__device__ __forceinline__ float dppf(float x) {
  int i = __float_as_int(x);
  int r = __builtin_amdgcn_update_dpp(i, i, CTRL, 0xF, 0xF, false);
  return __int_as_float(r);
}

// Per-thread twiddles, scalars only (compile-time indexed) -> VGPRs.
struct Tw {
  float tc6, ts6;            // cos/sin(pi*lane/64) for the register stage
  float g[6];                // +1 lower lane of pair, -1 upper
  float dwr[6], dwi[6];      // DIF post-mul: up ? conj(w) : 1   (DIT uses dwr,-dwi)
};

// butterfly d = partner + g*own, via DPP (H=1,2)
template<int CTRL, int S>
__device__ __forceinline__ v2f bfly_dpp(v2f m, const Tw& tw) {
  v2f t = (v2f){dppf<CTRL>(m.x), dppf<CTRL>(m.y)};
  return t + splat2(tw.g[S]) * m;
}
// butterfly via ds_swizzle (H=4,8,16): OFS = (H<<10)|0x1F
template<int OFS, int S>
__device__ __forceinline__ v2f bfly_swz(v2f m, const Tw& tw) {
  v2f t;
  t.x = __int_as_float(__builtin_amdgcn_ds_swizzle(__float_as_int(m.x), OFS));
  t.y = __int_as_float(__builtin_amdgcn_ds_swizzle(__float_as_int(m.y), OFS));
  return t + splat2(tw.g[S]) * m;
}
// butterfly via ds_bpermute (H=32): bp32 = (lane^32)<<2, full-wave64 permute
__device__ __forceinline__ v2f bfly_bp32(v2f m, int bp32, float g5) {
  v2f t;
  t.x = __int_as_float(__builtin_amdgcn_ds_bpermute(bp32, __float_as_int(m.x)));
  t.y = __int_as_float(__builtin_amdgcn_ds_bpermute(bp32, __float_as_int(m.y)));
  return t + splat2(g5) * m;
}

template<int S> __device__ __forceinline__ v2f twd(v2f d, const Tw& tw) {  // dif post-mul
  return d * splat2(tw.dwr[S]) + swapv(d) * (v2f){-tw.dwi[S], tw.dwi[S]};
}
template<int S> __device__ __forceinline__ v2f twc(v2f a, const Tw& tw) {  // dit pre-mul (conj)
  return a * splat2(tw.dwr[S]) + swapv(a) * (v2f){tw.dwi[S], -tw.dwi[S]};
}

// Forward 128-pt DIF: natural-order input -> bit-reversed-order slots.
__device__ __forceinline__ void dif128(v2f& A, v2f& B, const Tw& tw, int bp32) {
  { // register stage h=64: w = e^{-i*pi*lane/64}
    v2f d = A - B;
    A = A + B;
    B = d * splat2(tw.tc6) + swapv(d) * (v2f){tw.ts6, -tw.ts6};
  }
  A = twd<5>(bfly_bp32(A, bp32, tw.g[5]), tw);  B = twd<5>(bfly_bp32(B, bp32, tw.g[5]), tw);
  A = twd<4>(bfly_swz<0x401F, 4>(A, tw), tw);   B = twd<4>(bfly_swz<0x401F, 4>(B, tw), tw);
  A = twd<3>(bfly_swz<0x201F, 3>(A, tw), tw);   B = twd<3>(bfly_swz<0x201F, 3>(B, tw), tw);
  A = twd<2>(bfly_swz<0x101F, 2>(A, tw), tw);   B = twd<2>(bfly_swz<0x101F, 2>(B, tw), tw);
  A = twd<1>(bfly_dpp<0x4E, 1>(A, tw), tw);     B = twd<1>(bfly_dpp<0x4E, 1>(B, tw), tw);
  A = bfly_dpp<0xB1, 0>(A, tw);                 B = bfly_dpp<0xB1, 0>(B, tw);  // stage 0: w=1
}

// Inverse (unnormalized) 128-pt DIT: bit-reversed slots -> natural order.
__device__ __forceinline__ void dit128(v2f& A, v2f& B, const Tw& tw, int bp32) {
  A = bfly_dpp<0xB1, 0>(A, tw);                 B = bfly_dpp<0xB1, 0>(B, tw);  // stage 0: w=1
  A = bfly_dpp<0x4E, 1>(twc<1>(A, tw), tw);     B = bfly_dpp<0x4E, 1>(twc<1>(B, tw), tw);
  A = bfly_swz<0x101F, 2>(twc<2>(A, tw), tw);   B = bfly_swz<0x101F, 2>(twc<2>(B, tw), tw);
  A = bfly_swz<0x201F, 3>(twc<3>(A, tw), tw);   B = bfly_swz<0x201F, 3>(twc<3>(B, tw), tw);
  A = bfly_swz<0x401F, 4>(twc<4>(A, tw), tw);   B = bfly_swz<0x401F, 4>(twc<4>(B, tw), tw);
  A = bfly_bp32(twc<5>(A, tw), bp32, tw.g[5]);  B = bfly_bp32(twc<5>(B, tw), bp32, tw.g[5]);
  { // register stage h=64: w = e^{+i*pi*lane/64}
    v2f m = B * splat2(tw.tc6) + swapv(B) * (v2f){-tw.ts6, tw.ts6};
    B = A - m;
    A = A + m;
  }
}

// Pre-scramble H into workspace: hp[px][py] = H[br(py)][br(px)] * (1/N^2).
__global__ void __launch_bounds__(256) init_hpre(const float* __restrict__ H,
                                                 float2* __restrict__ hp) {
  int i = blockIdx.x * blockDim.x + threadIdx.x;
  if (i >= NP * NP) return;
  int px = i >> 7, py = i & (NP - 1);
  int ky = br7(py), kx = br7(px);
  hp[px * NP + py] = make_float2(H[(ky * NP + kx) * 2 + 0] * INV_N2,
                                 H[(ky * NP + kx) * 2 + 1] * INV_N2);
}

// Per-n shift ramps at bit-reversed slot positions.
__global__ void __launch_bounds__(256) init_ramp(const float* __restrict__ shifts,
                                                 const int* __restrict__ indices,
                                                 float2* __restrict__ rampy,
                                                 float2* __restrict__ rampx) {
  int i = blockIdx.x * blockDim.x + threadIdx.x;
  if (i >= 2 * BATCH * NP) return;
  int which = (i >= BATCH * NP) ? 1 : 0;
  int r = i - which * BATCH * NP;
  int n = r >> 7, slot = r & (NP - 1);
  int pos = indices[n];
  float sh = shifts[2 * pos + which];
  int k = br7(slot);
  float f = (float)(k < 64 ? k : k - 128) * (1.f / 128.f);
  float s, c;
  __sincosf(-6.28318530717959f * f * sh, &s, &c);
  if (!which) rampy[n * NP + slot] = make_float2(c * INV_N2, s * INV_N2);
  else        rampx[n * NP + slot] = make_float2(c, s);
}

// Precompute T = obja * exp(i*objp) over the full object volume.
__global__ void __launch_bounds__(256) init_T(const float* __restrict__ obja,
                                              const float* __restrict__ objp,
                                              float2* __restrict__ T) {
  int i = blockIdx.x * 256 + threadIdx.x;
  if (i >= OMODE * NZ * NYX * NYX) return;
  float a = obja[i], ph = objp[i];
  float s, c;
  __sincosf(ph, &s, &c);
  T[i] = make_float2(a * c, a * s);
}

// Sum the 8 (o,p) partials per batch element, applying omode occupancy here.
// part tile is TRANSPOSED: [blk][kx][ky].
__global__ void __launch_bounds__(256) reduce_dp(const float* __restrict__ part,
                                                 const float* __restrict__ occu,
                                                 float* __restrict__ dp) {
  int i = blockIdx.x * 256 + threadIdx.x;
  if (i >= BATCH * NP * NP) return;
  int n = i >> 14;
  int r = i & (NP * NP - 1);
  int ky = r >> 7, kx = r & (NP - 1);
  const float* b = part + ((size_t)n * 8 << 14) + (kx << 7) + ky;
  float w0 = occu[0], w1 = occu[1];
  float s = 0.f;
#pragma unroll
  for (int j = 0; j < 8; ++j) s = fmaf(b[(size_t)j << 14], (j < 4 ? w0 : w1), s);
  dp[i] = s;
}

__global__ void
__attribute__((amdgpu_flat_work_group_size(1024, 1024), amdgpu_waves_per_eu(4, 4)))
ptycho_chain(
    const float* __restrict__ obja, const float* __restrict__ objp,
    const float* __restrict__ probe, const float* __restrict__ shifts,
    const float* __restrict__ H, const float2* __restrict__ hpre,
    const float2* __restrict__ rampy, const float2* __restrict__ rampx,
    const float2* __restrict__ Tpre,
    const float* __restrict__ occu, const int* __restrict__ indices,
    const int* __restrict__ crop, float* __restrict__ dp,
    float* __restrict__ part, int mode_ws, int mode_T)
{
  extern __shared__ v2f fld[];             // [128][LSTR] interleaved re/im

  const int blk  = blockIdx.x;             // n*8 + o*4 + p
  const int n    = blk >> 3;
  const int o    = (blk >> 2) & 1;
  const int p    = blk & 3;
  const int tid  = threadIdx.x;
  const int wid  = tid >> 6;               // 16 waves
  const int lane = tid & 63;
  const int bp32 = (lane ^ 32) << 2;       // ds_bpermute byte index for xor-32

  const int   pos = indices[n];
  const int   cy  = crop[2 * pos + 0];
  const int   cx  = crop[2 * pos + 1];
  const float wocc = occu[o];

  // ---- twiddles ----------------------------------------------------------
  Tw tw;
  tw.g[0] = ((lane >> 0) & 1) ? -1.f : 1.f;
#pragma unroll
  for (int s = 1; s < 6; ++s) {
    int h = 1 << s;
    int j = lane & (h - 1);
    float ang = 3.14159265358979f * (float)j / (float)h;
    float ts_, tc_;
    __sincosf(ang, &ts_, &tc_);
    bool up = (lane >> s) & 1;
    tw.g[s]   = up ? -1.f : 1.f;
    tw.dwr[s] = up ? tc_ : 1.f;
    tw.dwi[s] = up ? -ts_ : 0.f;
  }
  __sincosf(3.14159265358979f * (float)lane * (1.f / 64.f), &tw.ts6, &tw.tc6);

  // ---- P0: load probe rows + forward row FFT (ILP-4) --------------------
  const v2f* probe2 = (const v2f*)probe;
#pragma unroll 1
  for (int k0 = 0; k0 < 8; k0 += 4) {
    int r0 = wid * 8 + k0;
    v2f A[4], B[4];
#pragma unroll
    for (int kk = 0; kk < 4; ++kk) {
      A[kk] = probe2[(p * NP + r0 + kk) * NP + lane];
      B[kk] = probe2[(p * NP + r0 + kk) * NP + lane + 64];
    }
#pragma unroll
    for (int kk = 0; kk < 4; ++kk) dif128(A[kk], B[kk], tw, bp32);
#pragma unroll
    for (int kk = 0; kk < 4; ++kk) {
      fld[(r0 + kk) * LSTR + lane]      = A[kk];
      fld[(r0 + kk) * LSTR + lane + 64] = B[kk];
    }
  }
  __syncthreads();

  // fallback-only multiplies (no workspace)
  auto ramp_mul_fb = [&](v2f& A, v2f& B, int c) {
    float sh0v = shifts[2 * pos], sh1v = shifts[2 * pos + 1];
    int kxc = br7(c);
    float fx = (float)(kxc < 64 ? kxc : kxc - 128) * (1.f / 128.f);
    int ky0 = br7(lane);
    float fy0 = (float)(ky0 < 64 ? ky0 : ky0 - 128) * (1.f / 128.f);
    int ky1 = ky0 + 1;
    float fy1 = (float)(ky1 < 64 ? ky1 : ky1 - 128) * (1.f / 128.f);
    float com = fx * sh1v;
    float s0, c0_, s1, c1_;
    __sincosf(-6.28318530717959f * (fy0 * sh0v + com), &s0, &c0_);
    __sincosf(-6.28318530717959f * (fy1 * sh0v + com), &s1, &c1_);
    A = cmulv(A, c0_ * INV_N2, s0 * INV_N2);
    B = cmulv(B, c1_ * INV_N2, s1 * INV_N2);
  };
  auto h_mul_fb = [&](v2f& A, v2f& B, int c) {
    int kx = br7(c), ky0 = br7(lane);
    float hr0 = H[(ky0 * NP + kx) * 2], hi0 = H[(ky0 * NP + kx) * 2 + 1];
    float hr1 = H[((ky0 + 1) * NP + kx) * 2], hi1 = H[((ky0 + 1) * NP + kx) * 2 + 1];
    A = cmulv(A, hr0 * INV_N2, hi0 * INV_N2);
    B = cmulv(B, hr1 * INV_N2, hi1 * INV_N2);
  };

  // ---- column phase: Fcol, freq multiply, invCol (ILP-4) ----------------
  auto cphase = [&](int mode) {
    v2f ry0, ry1;
    if (mode == 0 && mode_ws) {
      float2 t0 = rampy[n * NP + lane];
      float2 t1 = rampy[n * NP + lane + 64];
      ry0 = (v2f){t0.x, t0.y}; ry1 = (v2f){t1.x, t1.y};
    }
#pragma unroll 1
    for (int k0 = 0; k0 < 8; k0 += 4) {
      int c0 = wid * 8 + k0;
      float2 h0[4], h1[4], rx[4];
      if (mode == 1 && mode_ws) {
#pragma unroll
        for (int kk = 0; kk < 4; ++kk) {
          h0[kk] = hpre[(c0 + kk) * NP + lane];
          h1[kk] = hpre[(c0 + kk) * NP + lane + 64];
        }
      }
      if (mode == 0 && mode_ws) {
#pragma unroll
        for (int kk = 0; kk < 4; ++kk) rx[kk] = rampx[n * NP + c0 + kk];
      }
      v2f A[4], B[4];
#pragma unroll
      for (int kk = 0; kk < 4; ++kk) {
        A[kk] = fld[lane * LSTR + c0 + kk];
        B[kk] = fld[(lane + 64) * LSTR + c0 + kk];
      }
#pragma unroll
      for (int kk = 0; kk < 4; ++kk) dif128(A[kk], B[kk], tw, bp32);
      if (mode == 0) {
        if (mode_ws) {
#pragma unroll
          for (int kk = 0; kk < 4; ++kk) {
            v2f m;
            m = cmulv(ry0, rx[kk].x, rx[kk].y); A[kk] = cmulvv(A[kk], m);
            m = cmulv(ry1, rx[kk].x, rx[kk].y); B[kk] = cmulvv(B[kk], m);
          }
        } else {
#pragma unroll
          for (int kk = 0; kk < 4; ++kk) ramp_mul_fb(A[kk], B[kk], c0 + kk);
        }
      } else {
        if (mode_ws) {
#pragma unroll
          for (int kk = 0; kk < 4; ++kk) {
            A[kk] = cmulv(A[kk], h0[kk].x, h0[kk].y);
            B[kk] = cmulv(B[kk], h1[kk].x, h1[kk].y);
          }
        } else {
#pragma unroll
          for (int kk = 0; kk < 4; ++kk) h_mul_fb(A[kk], B[kk], c0 + kk);
        }
      }
#pragma unroll
      for (int kk = 0; kk < 4; ++kk) dit128(A[kk], B[kk], tw, bp32);
#pragma unroll
      for (int kk = 0; kk < 4; ++kk) {
        fld[lane * LSTR + c0 + kk]        = A[kk];
        fld[(lane + 64) * LSTR + c0 + kk] = B[kk];
      }
    }
    __syncthreads();
  };

  // ---- row phase: invRow, multiply T(z), Frow (ILP-4) -------------------
  auto rphase = [&](int z) {
#pragma unroll 1
    for (int k0 = 0; k0 < 8; k0 += 4) {
      int r0 = wid * 8 + k0;
      size_t ob = ((size_t)(o * NZ + z) * NYX + (size_t)(cy + r0)) * NYX + cx;
      v2f A[4], B[4];
#pragma unroll
      for (int kk = 0; kk < 4; ++kk) {
        A[kk] = fld[(r0 + kk) * LSTR + lane];
        B[kk] = fld[(r0 + kk) * LSTR + lane + 64];
      }
      if (mode_T) {
        float2 t0[4], t1[4];
#pragma unroll
        for (int kk = 0; kk < 4; ++kk) {
          t0[kk] = Tpre[ob + (size_t)kk * NYX + lane];
          t1[kk] = Tpre[ob + (size_t)kk * NYX + lane + 64];
        }
#pragma unroll
        for (int kk = 0; kk < 4; ++kk) dit128(A[kk], B[kk], tw, bp32);
#pragma unroll
        for (int kk = 0; kk < 4; ++kk) {
          A[kk] = cmulv(A[kk], t0[kk].x, t0[kk].y);
          B[kk] = cmulv(B[kk], t1[kk].x, t1[kk].y);
        }
      } else {
        float pa0[4], ph0[4], pa1[4], ph1[4];
#pragma unroll
        for (int kk = 0; kk < 4; ++kk) {
          pa0[kk] = obja[ob + (size_t)kk * NYX + lane];
          ph0[kk] = objp[ob + (size_t)kk * NYX + lane];
          pa1[kk] = obja[ob + (size_t)kk * NYX + lane + 64];
          ph1[kk] = objp[ob + (size_t)kk * NYX + lane + 64];
        }
#pragma unroll
        for (int kk = 0; kk < 4; ++kk) dit128(A[kk], B[kk], tw, bp32);
#pragma unroll
        for (int kk = 0; kk < 4; ++kk) {
          float s, c;
          __sincosf(ph0[kk], &s, &c); A[kk] = cmulv(A[kk], pa0[kk] * c, pa0[kk] * s);
          __sincosf(ph1[kk], &s, &c); B[kk] = cmulv(B[kk], pa1[kk] * c, pa1[kk] * s);
        }
      }
#pragma unroll
      for (int kk = 0; kk < 4; ++kk) dif128(A[kk], B[kk], tw, bp32);
#pragma unroll
      for (int kk = 0; kk < 4; ++kk) {
        fld[(r0 + kk) * LSTR + lane]      = A[kk];
        fld[(r0 + kk) * LSTR + lane + 64] = B[kk];
      }
    }
    __syncthreads();
  };

  cphase(0);        // Fcol + ramp + invCol  (completes probe shift)
  rphase(0);        // invRow + T0 + Frow
#pragma unroll 1
  for (int z = 1; z < NZ; ++z) {
    cphase(1);      // Fcol + H + invCol     (propagation z-1 -> z)
    rphase(z);      // invRow + Tz + Frow
  }

  // ---- final column FFT -> |.|^2 -> store (transposed part tile) --------
#pragma unroll 1
  for (int k0 = 0; k0 < 8; k0 += 4) {
    int c0 = wid * 8 + k0;
    v2f A[4], B[4];
#pragma unroll
    for (int kk = 0; kk < 4; ++kk) {
      A[kk] = fld[lane * LSTR + c0 + kk];
      B[kk] = fld[(lane + 64) * LSTR + c0 + kk];
    }
#pragma unroll
    for (int kk = 0; kk < 4; ++kk) dif128(A[kk], B[kk], tw, bp32);
    int ky0 = br7(lane);
#pragma unroll
    for (int kk = 0; kk < 4; ++kk) {
      float m0 = fmaf(A[kk].x, A[kk].x, A[kk].y * A[kk].y);
      float m1 = fmaf(B[kk].x, B[kk].x, B[kk].y * B[kk].y);
      if (mode_ws) {
        size_t b0 = ((size_t)blk << 14) + (size_t)br7(c0 + kk) * NP;
        part[b0 + ky0]     = m0;    // occupancy weight applied in reduce_dp
        part[b0 + ky0 + 1] = m1;
      } else {
        size_t base = ((size_t)n << 14);
        atomicAdd(&dp[base + (size_t)ky0 * NP + br7(c0 + kk)],       m0 * wocc);
        atomicAdd(&dp[base + (size_t)(ky0 + 1) * NP + br7(c0 + kk)], m1 * wocc);
      }
    }
  }
}

extern "C" void kernel_launch(void* const* d_in, const int* in_sizes, int n_in,
                              void* d_out, int out_size, void* d_ws, size_t ws_size,
                              hipStream_t stream) {
  const float* obja   = (const float*)d_in[0];
  const float* objp   = (const float*)d_in[1];
  const float* probe  = (const float*)d_in[2];
  const float* shifts = (const float*)d_in[3];
  const float* H      = (const float*)d_in[4];
  const float* occu   = (const float*)d_in[5];
  const int*   indices = (const int*)d_in[6];
  const int*   crop    = (const int*)d_in[7];
  float* dp = (float*)d_out;

  const size_t part_bytes  = (size_t)BATCH * OMODE * PMODE * NP * NP * sizeof(float); // 32 MB
  const size_t hpre_bytes  = (size_t)NP * NP * sizeof(float2);                        // 128 KB
  const size_t ramp_bytes  = (size_t)BATCH * NP * sizeof(float2);                     // 64 KB each
  const size_t T_bytes     = (size_t)OMODE * NZ * NYX * NYX * sizeof(float2);         // 33.5 MB
  const size_t need_ws = part_bytes + hpre_bytes + 2 * ramp_bytes;
  const size_t need_T  = need_ws + T_bytes;

  int mode_ws = (ws_size >= need_ws) ? 1 : 0;
  int mode_T  = (ws_size >= need_T) ? 1 : 0;
  float*  part  = (float*)d_ws;
  float2* hpre  = (float2*)((char*)d_ws + part_bytes);
  float2* rampy = (float2*)((char*)d_ws + part_bytes + hpre_bytes);
  float2* rampx = (float2*)((char*)d_ws + part_bytes + hpre_bytes + ramp_bytes);
  float2* Tpre  = (float2*)((char*)d_ws + need_ws);

  if (mode_ws) {
    hipLaunchKernelGGL(init_hpre, dim3((NP * NP + 255) / 256), dim3(256), 0,
                       stream, H, hpre);
    hipLaunchKernelGGL(init_ramp, dim3((2 * BATCH * NP + 255) / 256), dim3(256), 0,
                       stream, shifts, indices, rampy, rampx);
  } else {
    // atomic fallback accumulates -> must zero output every call
    hipMemsetAsync(d_out, 0, (size_t)out_size * sizeof(float), stream);
  }
  if (mode_T) {
    hipLaunchKernelGGL(init_T, dim3((OMODE * NZ * NYX * NYX + 255) / 256), dim3(256),
                       0, stream, obja, objp, Tpre);
  }

  const int lds_bytes = NP * LSTR * (int)sizeof(float2);  // 132096
  hipFuncSetAttribute((const void*)ptycho_chain,
                      hipFuncAttributeMaxDynamicSharedMemorySize, lds_bytes);
  hipLaunchKernelGGL(ptycho_chain, dim3(BATCH * OMODE * PMODE), dim3(1024),
                     lds_bytes, stream,
                     obja, objp, probe, shifts, H, hpre, rampy, rampx, Tpre,
                     occu, indices, crop, dp, part, mode_ws, mode_T);
  if (mode_ws) {
    hipLaunchKernelGGL(reduce_dp, dim3((BATCH * NP * NP + 255) / 256), dim3(256),
                       0, stream, part, occu, dp);
  }
}